// Round 8
// baseline (133.947 us; speedup 1.0000x reference)
//
#include <hip/hip_runtime.h>
#include <math.h>

// ---------------------------------------------------------------------------
// GaussianQuant — MFMA-filtered argmax, R20.
// score[n,k] = sum_d p*c + q*c^2;  u=[p,q], v=[c,c^2], score = u.v  (K=64)
// fp16 HI-ONLY approx, rigorous per-k error:
//   err_k <= 1.05e-3 * (||p||2*||c_k||2 + ||q||2*||c_k^2||2)   (Cauchy-Schwarz)
// R20 (vs R19 post-mortem): all chunked-staging filters land 31-44us vs the
// 16.6us MFMA floor; the common cost is the vmcnt(0)+barrier drain per chunk
// (m97 stall) x4..8. R20 = PERSISTENT-B filter: block owns HALF a split
// (512 k = 64KB LDS, static max), staged ONCE via global_load_lds, ONE
// barrier, then a free-running loop {4 ds_read_b128, 32 MFMA, fused max3}
// per tile-pair with A register-resident (8 rowtiles/wave). ZERO barriers in
// the main loop. Grid (32 rowchunks x 32 halfsplits) = 1024 blocks,
// launch_bounds(256,2) -> 2 blocks/CU (128KB LDS), 8 waves/CU.
// Per-CU: MFMA 39.7kcy (floor), ds_read 6.1k, max3 ~4k/SIMD — all hidden.
// Columns now (halfsplit, c16): 512 cols of 32 k. CN1/CN2[512], W1 16MB fp16
// [hs][row][16]. Merge: w[8] groups; seed k0 = hs*512 + (lane&31)*16 + c16.
// ---------------------------------------------------------------------------

typedef _Float16 half8 __attribute__((ext_vector_type(8)));
typedef float f32x4 __attribute__((ext_vector_type(4)));

#define DIM 32
#define NROWS 16384
#define KSIZE 16384
#define NHS 32                          // halfsplits
#define HSK 512                         // k per halfsplit
#define NCOL 512                        // columns = (hs, c16)

// ws layout (bytes); [0,8192) zeroed by memset each launch
#define WS_M1   0                       // 32 float (atomicMax targets)
#define WS_KL   256                     // 1 double (atomicAdd target)
#define WS_CN1  1024                    // 512 float (atomicMax: max ||c_k||)
#define WS_CN2  3072                    // 512 float (atomicMax: max ||c_k^2||)
#define WS_PQ   8192                    // 4 MB fp32 [row][64]
#define WS_AH   (WS_PQ + 4194304)       // 2 MB fp16 [row][64]
#define WS_BH   (WS_AH + 2097152)       // 2 MB fp16 [k][64] PRE-SWIZZLED
#define WS_W1   (WS_BH + 2097152)       // 16 MB fp16 [hs][row][16]

// Fused prep, 1024 blocks: [0,512) pack codebook (swizzled) + per-dim max +
// per-column norm maxima; [512,1024) compute p,q + fp16 pack + KL partial.
__global__ __launch_bounds__(256) void prep_kernel(const float* __restrict__ cb,
                                                   const float* __restrict__ z,
                                                   _Float16* __restrict__ Bh,
                                                   float* __restrict__ M1,
                                                   float* __restrict__ CN1,
                                                   float* __restrict__ CN2,
                                                   float* __restrict__ PQ,
                                                   _Float16* __restrict__ Ah,
                                                   double* __restrict__ klsum) {
  const int w = threadIdx.x >> 6, l = threadIdx.x & 63;
  const int sub = l >> 5, d = l & 31;
  if (blockIdx.x < 512) {
    __shared__ float lm[8][DIM];
    float m = 0.0f;
#pragma unroll
    for (int i = 0; i < 4; ++i) {
      const int k = blockIdx.x * 32 + i * 8 + w * 2 + sub;
      const float c = cb[k * DIM + d];
      // swizzled slot layout: logical slot s (8 halfs) stored at s ^ (k&7)
      const int key = k & 7;
      const int sc = (d >> 3) ^ key;          // c-part: logical slot d>>3
      const int sq = (4 + (d >> 3)) ^ key;    // c^2-part: logical slot 4+d>>3
      Bh[(size_t)k * 64 + sc * 8 + (d & 7)] = (_Float16)c;
      Bh[(size_t)k * 64 + sq * 8 + (d & 7)] = (_Float16)(c * c);
      m = fmaxf(m, fabsf(c));
      // per-k norms -> per-column maxima (col = (k>>9)*16 + (k&15))
      float s2 = c * c, s4 = c * c * c * c;
#pragma unroll
      for (int mask = 1; mask <= 16; mask <<= 1) {
        s2 += __shfl_xor(s2, mask);
        s4 += __shfl_xor(s4, mask);
      }
      if (d == 0) {
        const int col = (k >> 9) * 16 + (k & 15);
        atomicMax((unsigned*)&CN1[col], __float_as_uint(sqrtf(s2)));
        atomicMax((unsigned*)&CN2[col], __float_as_uint(sqrtf(s4)));
      }
    }
    lm[threadIdx.x >> 5][d] = m;
    __syncthreads();
    if (threadIdx.x < DIM) {
      float x = lm[0][threadIdx.x];
#pragma unroll
      for (int i = 1; i < 8; ++i) x = fmaxf(x, lm[i][threadIdx.x]);
      atomicMax((unsigned*)&M1[threadIdx.x], __float_as_uint(x));
    }
  } else {
    const int blk = blockIdx.x - 512;
    double kacc = 0.0;
#pragma unroll 1
    for (int i = 0; i < 4; ++i) {
      const int row = blk * 32 + i * 8 + w * 2 + sub;
      const int t = row >> 3, c = row & 7;
      const float mu = z[t * 512 + d * 8 + c];
      float lv = z[t * 512 + 256 + d * 8 + c];
      lv = fminf(fmaxf(lv, -30.0f), 20.0f);
      const float stdv = expf(0.5f * lv);
      const float iv = 1.0f / (stdv * stdv);   // identical to R2 expression
      const float p = mu * iv;
      const float q = 0.5f * (1.0f - iv);
      PQ[(size_t)row * 64 + d] = p;
      PQ[(size_t)row * 64 + 32 + d] = q;
      Ah[(size_t)row * 64 + d] = (_Float16)p;
      Ah[(size_t)row * 64 + 32 + d] = (_Float16)q;
      kacc += (double)(mu * mu + stdv * stdv - 1.0f - lv);
    }
#pragma unroll
    for (int off = 32; off > 0; off >>= 1) kacc += __shfl_down(kacc, off);
    __shared__ double wsum[4];
    if (l == 0) wsum[w] = kacc;
    __syncthreads();
    if (threadIdx.x == 0)
      atomicAdd(klsum, (wsum[0] + wsum[1]) + (wsum[2] + wsum[3]));
  }
}

// async global->LDS, 16B per lane; dest must be linear in lane order.
__device__ __forceinline__ void gload_lds16(const _Float16* g, _Float16* l) {
  __builtin_amdgcn_global_load_lds(
      (__attribute__((address_space(1))) void*)(g),
      (__attribute__((address_space(3))) void*)(l), 16, 0, 0);
}

// grid (32, 32): x = rowchunk (512 rows), y = halfsplit (512 k).
// 4 waves x 128 rows each (8 rowtiles, A = 64 VGPR resident).
// B = 64KB LDS, loaded ONCE; one barrier; main loop barrier-free.
__global__ __launch_bounds__(256, 2) void filter_kernel(const _Float16* __restrict__ Ah,
                                                        const _Float16* __restrict__ Bh,
                                                        _Float16* __restrict__ W1) {
  __shared__ _Float16 sB[32768];   // 64 KB: 32 tiles x 16 k x 64 halfs
  const int tid = threadIdx.x;
  const int lane = tid & 63;
  const int wave = tid >> 6;
  const int hs = blockIdx.y;
  const int rowbase = blockIdx.x * 512 + wave * 128;   // 8 rowtiles of 16
  const int c16 = lane & 15, quad = lane >> 4;

  // stage the whole 64KB B region (linear copy: Bh pre-swizzled in prep)
  const _Float16* gB = Bh + (size_t)hs * HSK * 64;
#pragma unroll
  for (int j = 0; j < 16; ++j)
    gload_lds16(gB + j * 2048 + tid * 8, &sB[j * 2048 + tid * 8]);

  // A panel: 8 rowtiles x (p, q) fragments = 64 VGPR (lands during B DMA)
  half8 uh0[8], uh1[8];
#pragma unroll
  for (int rt = 0; rt < 8; ++rt) {
    const size_t abase = (size_t)(rowbase + rt * 16 + c16) * 64 + quad * 8;
    uh0[rt] = *(const half8*)(Ah + abase);
    uh1[rt] = *(const half8*)(Ah + abase + 32);
  }

  float a1[8][4];
#pragma unroll
  for (int rt = 0; rt < 8; ++rt)
#pragma unroll
    for (int r = 0; r < 4; ++r) a1[rt][r] = -INFINITY;

  const f32x4 fzero = {0.f, 0.f, 0.f, 0.f};
  // swizzled read offsets (halfs): row c16, physical slot = logical ^ (c16&7)
  const int key = c16 & 7;
  const int rs0h = c16 * 64 + (quad ^ key) * 8;         // p-part (slots 0-3)
  const int rs1h = c16 * 64 + ((quad + 4) ^ key) * 8;   // q-part (slots 4-7)

  __syncthreads();   // B landed (compiler drains vmcnt before barrier)

#pragma unroll 1
  for (int tp = 0; tp < 16; ++tp) {          // 16 tile-pairs, barrier-free
    const _Float16* b0 = sB + (2 * tp) * 1024;
    const _Float16* b1 = b0 + 1024;
    const half8 x0 = *(const half8*)(b0 + rs0h);
    const half8 x1 = *(const half8*)(b0 + rs1h);
    const half8 y0 = *(const half8*)(b1 + rs0h);
    const half8 y1 = *(const half8*)(b1 + rs1h);
#pragma unroll
    for (int rt = 0; rt < 8; ++rt) {
      f32x4 h0 = __builtin_amdgcn_mfma_f32_16x16x32_f16(uh0[rt], x0, fzero, 0, 0, 0);
      h0 = __builtin_amdgcn_mfma_f32_16x16x32_f16(uh1[rt], x1, h0, 0, 0, 0);
      f32x4 h1 = __builtin_amdgcn_mfma_f32_16x16x32_f16(uh0[rt], y0, fzero, 0, 0, 0);
      h1 = __builtin_amdgcn_mfma_f32_16x16x32_f16(uh1[rt], y1, h1, 0, 0, 0);
#pragma unroll
      for (int r = 0; r < 4; ++r)
        a1[rt][r] = fmaxf(fmaxf(h0[r], h1[r]), a1[rt][r]);   // v_max3
    }
  }

  // W1 fp16 [hs][row][16]: block-exclusive contiguous 16KB, no RMW.
  // Low-clamp kills -inf; high-side rounding covered by merge's 5e-4*|w|.
#pragma unroll
  for (int rt = 0; rt < 8; ++rt)
#pragma unroll
    for (int r = 0; r < 4; ++r) {
      const int row_r = rowbase + rt * 16 + quad * 4 + r;   // C: row=quad*4+r
      W1[((size_t)hs * NROWS + row_r) * 16 + c16] =
          (_Float16)fmaxf(a1[rt][r], -65504.0f);
    }
}

// exact fp32 score, p/q broadcast from LDS (identical formula to R2)
__device__ __forceinline__ float exact_score(const float4* __restrict__ cb4,
                                             const float4* __restrict__ spq,
                                             int k) {
  float s0 = 0.0f, s1 = 0.0f, s2 = 0.0f, s3 = 0.0f;
#pragma unroll
  for (int m = 0; m < 8; ++m) {
    const float4 cv = cb4[k * 8 + m];
    const float4 pv = spq[m];        // p[4m..4m+3]
    const float4 qv = spq[8 + m];    // q[4m..4m+3]
    s0 = fmaf(cv.x, fmaf(qv.x, cv.x, pv.x), s0);
    s1 = fmaf(cv.y, fmaf(qv.y, cv.y, pv.y), s1);
    s2 = fmaf(cv.z, fmaf(qv.z, cv.z, pv.z), s2);
    s3 = fmaf(cv.w, fmaf(qv.w, cv.w, pv.w), s3);
  }
  return (s0 + s1) + (s2 + s3);
}

// 1 wave per row; 4 rows per block. 512 columns of 32 k. Seed E* by exact
// rescan of the argmax column (j = lane&31, duplicated halves), then full
// rescan of every column with w + Btot_col >= E*.
__global__ __launch_bounds__(256, 4) void merge_kernel(const float* __restrict__ PQ,
                                                       const float* __restrict__ cb,
                                                       const _Float16* __restrict__ W1,
                                                       const float* __restrict__ CN1,
                                                       const float* __restrict__ CN2,
                                                       const double* __restrict__ klsum,
                                                       float* __restrict__ out0,
                                                       float* __restrict__ out1,
                                                       float* __restrict__ out2) {
  __shared__ float4 spq_s[4][16];
  const int lane = threadIdx.x & 63;
  const int wave = threadIdx.x >> 6;
  const int row = blockIdx.x * 4 + wave;

  if (lane < 16)
    spq_s[wave][lane] = ((const float4*)(PQ + (size_t)row * 64))[lane];
  __syncthreads();
  const float4* spq = spq_s[wave];
  const float4* __restrict__ cb4 = (const float4*)cb;

  // per-row norms ||p||2, ||q||2
  float sp = 0.0f, sq = 0.0f;
  if (lane < DIM) {
    const float pd = ((const float*)spq)[lane];
    const float qd = ((const float*)spq)[32 + lane];
    sp = pd * pd;
    sq = qd * qd;
  }
#pragma unroll
  for (int off = 1; off < 32; off <<= 1) {
    sp += __shfl_xor(sp, off);
    sq += __shfl_xor(sq, off);
  }
  const float pn = sqrtf(__shfl(sp, 0));
  const float qn = sqrtf(__shfl(sq, 0));

  // load 512 column maxima (fp16, layout [hs][row][16]); col = i*64 + lane
  float w[8];
#pragma unroll
  for (int i = 0; i < 8; ++i)
    w[i] = (float)W1[((size_t)(i * 4 + (lane >> 4)) * NROWS + row) * 16 + (lane & 15)];
  float As = w[0];
#pragma unroll
  for (int i = 1; i < 8; ++i) As = fmaxf(As, w[i]);
#pragma unroll
  for (int off = 1; off < 64; off <<= 1) As = fmaxf(As, __shfl_xor(As, off));
  const float slack = 2e-5f * (fabsf(As) + 1.0f) + 1e-3f;

  // per-column rigorous bounds + fp16-rounding term
  float bt[8];
#pragma unroll
  for (int i = 0; i < 8; ++i) {
    const int col = i * 64 + lane;
    bt[i] = 1.05e-3f * (pn * CN1[col] + qn * CN2[col]) + slack
            + 5e-4f * fabsf(w[i]);
  }

  // ---- seed: full exact rescan of (one) column achieving As ----
  int done_col = -1;
#pragma unroll
  for (int i = 0; i < 8; ++i) {
    if (done_col < 0) {
      const unsigned long long m = __ballot(w[i] == As);
      if (m) done_col = i * 64 + __builtin_ctzll(m);
    }
  }
  const int k0 = (done_col >> 4) * HSK + (lane & 31) * 16 + (done_col & 15);
  float best = exact_score(cb4, spq, k0);
  int bk = k0;
#pragma unroll
  for (int off = 1; off < 64; off <<= 1) {
    const float ov = __shfl_xor(best, off);
    const int ok = __shfl_xor(bk, off);
    if (ov > best || (ov == best && ok < bk)) { best = ov; bk = ok; }
  }
  const float Estar = best;   // exact score of a real k; all lanes agree

  // ---- full rescan of every other column that could still hold the max ----
#pragma unroll 1
  for (int i = 0; i < 8; ++i) {
    unsigned long long m = __ballot(w[i] + bt[i] >= Estar);
    if ((done_col >> 6) == i) m &= ~(1ull << (done_col & 63));
    while (m) {
      const int e = __builtin_ctzll(m);
      m &= m - 1;
      const int col = i * 64 + e;
      const int k = (col >> 4) * HSK + (lane & 31) * 16 + (col & 15);
      const float sc = exact_score(cb4, spq, k);
      if (sc > best || (sc == best && k < bk)) { best = sc; bk = k; }
    }
  }
  // final cross-lane argmax, min-k on ties (numpy first-max)
#pragma unroll
  for (int off = 1; off < 64; off <<= 1) {
    const float ov = __shfl_xor(best, off);
    const int ok = __shfl_xor(bk, off);
    if (ov > best || (ov == best && ok < bk)) { best = ov; bk = ok; }
  }
  if (lane == 0) out2[row] = (float)bk;
  const int tt = row >> 3, cc = row & 7;
  if (lane < DIM) out0[tt * 256 + lane * 8 + cc] = cb[bk * DIM + lane];
  if (blockIdx.x == 0 && threadIdx.x == 0)
    out1[0] = (float)(klsum[0] * (1.4426 * 0.5) / (double)NROWS);
}

extern "C" void kernel_launch(void* const* d_in, const int* in_sizes, int n_in,
                              void* d_out, int out_size, void* d_ws, size_t ws_size,
                              hipStream_t stream) {
  const float* z  = (const float*)d_in[0];
  const float* cb = (const float*)d_in[2];   // d_in[1]=noise unused (STE cancels)

  char* ws = (char*)d_ws;
  float*      M1 = (float*)(ws + WS_M1);
  double* klsum  = (double*)(ws + WS_KL);
  float*     CN1 = (float*)(ws + WS_CN1);
  float*     CN2 = (float*)(ws + WS_CN2);
  float*      PQ = (float*)(ws + WS_PQ);
  _Float16*   Ah = (_Float16*)(ws + WS_AH);
  _Float16*   Bh = (_Float16*)(ws + WS_BH);
  _Float16*   W1 = (_Float16*)(ws + WS_W1);

  float* out0 = (float*)d_out;            // 524288
  float* out1 = out0 + 524288;            // 1
  float* out2 = out1 + 1;                 // 16384

  (void)hipMemsetAsync(ws, 0, 8192, stream);   // M1, klsum, CN1, CN2 = 0
  prep_kernel<<<1024, 256, 0, stream>>>(cb, z, Bh, M1, CN1, CN2, PQ, Ah, klsum);
  dim3 fgrid(32, NHS);
  filter_kernel<<<fgrid, 256, 0, stream>>>(Ah, Bh, W1);
  merge_kernel<<<NROWS / 4, 256, 0, stream>>>(PQ, cb, W1, CN1, CN2, klsum,
                                              out0, out1, out2);
}